// Round 3
// baseline (846.584 us; speedup 1.0000x reference)
//
#include <hip/hip_runtime.h>
#include <hip/hip_bf16.h>

#define CHN 512
#define TLEN 2048
#define KSZ 5
#define BATCH 16

// ---------------------------------------------------------------------------
// k1: fused offset conv (out-ch 0..4), modulator conv (+sigmoid), and
// deformable sampling with diagonal weight. FP32 I/O. No global scratch.
// grid (TLEN/64, B), block (64 t, 4 c-groups).
// Phase A: conv(k=3,pad=1) over all 512 ci for the 10 needed outputs,
//          4-way split over ci, LDS tree reduce, build samp[64][5] in LDS.
// Phase B: each thread processes 128 channels at fixed t:
//          deformed[b,c,t] = sum_k (x[pf]*wf + x[pc]*wc)*sig * weight[c,c,k]
// ---------------------------------------------------------------------------
__global__ __launch_bounds__(256) void k1(const float* __restrict__ x,
    const float* __restrict__ ow, const float* __restrict__ ob,
    const float* __restrict__ mw, const float* __restrict__ mb,
    const float* __restrict__ wgt, float* __restrict__ out)
{
  int b  = blockIdx.y;
  int t0 = blockIdx.x*64;
  int tx = threadIdx.x;            // t within tile
  int cg = threadIdx.y;            // channel group
  int t  = t0 + tx;

  __shared__ float  red[4][64][10];
  __shared__ float4 samp[64][KSZ];

  // ---- Phase A: offset + modulator convs ----
  float acc[10];
  #pragma unroll
  for (int i=0;i<10;++i) acc[i]=0.f;
  const float* xb = x + (size_t)b*CHN*TLEN;
  int c0 = cg*128;
  for (int c=c0;c<c0+128;++c) {
    const float* xr = xb + (size_t)c*TLEN;
    float xm = (t>0)      ? xr[t-1] : 0.f;
    float xc = xr[t];
    float xp = (t<TLEN-1) ? xr[t+1] : 0.f;
    int wb = c*3;
    #pragma unroll
    for (int o=0;o<5;++o) {
      const float* wo = ow + o*(CHN*3) + wb;
      acc[o]   = fmaf(xm, wo[0], acc[o]);
      acc[o]   = fmaf(xc, wo[1], acc[o]);
      acc[o]   = fmaf(xp, wo[2], acc[o]);
      const float* wm = mw + o*(CHN*3) + wb;
      acc[5+o] = fmaf(xm, wm[0], acc[5+o]);
      acc[5+o] = fmaf(xc, wm[1], acc[5+o]);
      acc[5+o] = fmaf(xp, wm[2], acc[5+o]);
    }
  }
  #pragma unroll
  for (int i=0;i<10;++i) red[cg][tx][i] = acc[i];
  __syncthreads();
  if (cg==0) {
    #pragma unroll
    for (int i=0;i<10;++i)
      acc[i] = red[0][tx][i] + red[1][tx][i] + red[2][tx][i] + red[3][tx][i];
    #pragma unroll
    for (int k=0;k<KSZ;++k) {
      float off = acc[k]   + ob[k];
      float mv  = acc[5+k] + mb[k];
      float sig = 1.f/(1.f + expf(-mv));
      float pos = (float)(t + k - 2) + off;
      pos = fminf(fmaxf(pos, 0.f), (float)(TLEN-1));
      float pf = floorf(pos), pc = ceilf(pos);
      // matches ref: when pos integral, both weights are 0 -> sampled 0
      samp[tx][k] = make_float4(pf, pc, (pc-pos)*sig, (pos-pf)*sig);
    }
  }
  __syncthreads();

  // ---- Phase B: deformable sampling, 128 channels per thread ----
  float4 s[KSZ];
  #pragma unroll
  for (int k=0;k<KSZ;++k) s[k] = samp[tx][k];
  for (int c=c0;c<c0+128;++c) {
    const float* xr = xb + (size_t)c*TLEN;
    const float* wd = wgt + (size_t)c*(CHN*KSZ) + (size_t)c*KSZ;  // diag row
    float a = 0.f;
    #pragma unroll
    for (int k=0;k<KSZ;++k) {
      float xf = xr[(int)s[k].x];
      float xc = xr[(int)s[k].y];
      a = fmaf(xf*s[k].z + xc*s[k].w, wd[k], a);
    }
    out[((size_t)b*CHN + c)*TLEN + t] = a;
  }
}

// ---------------------------------------------------------------------------
// k2: fused rp1 conv(k=3,pad=1, 512->256) + ReLU + rp2 (1x1, 256->1) + bias.
// GEMM view: H[co,n] = W1[co, k=ci*3+r] * X[k, n=(b,t)], M=256, K=1536,
// N=32768, X[k,n] = deformed[b,ci,t+r-1] zero-padded.
// One block owns ALL of M for a 64-wide n-tile -> strength computed fully
// in-block (no global reduction). 256 threads, 16x4 register tile, BK=16.
// ---------------------------------------------------------------------------
__global__ __launch_bounds__(256) void k2(const float* __restrict__ def,
    const float* __restrict__ w1, const float* __restrict__ b1,
    const float* __restrict__ w2, const float* __restrict__ b2p,
    float* __restrict__ outs)
{
  int n0 = blockIdx.x*64;
  int b  = n0 / TLEN;
  int t0 = n0 % TLEN;              // 64 | 2048: tiles never straddle b
  int tid = threadIdx.x;

  __shared__ float Ws[16][256];
  __shared__ float Xs[16][64];
  __shared__ float Ss[64];

  float acc[16][4];
  #pragma unroll
  for (int i=0;i<16;++i)
    #pragma unroll
    for (int j=0;j<4;++j) acc[i][j]=0.f;

  int tr = tid>>4, tc = tid&15;     // compute: co-group(16 rows), n-group(4 cols)
  int kw = tid&15, cw = tid>>4;     // Ws staging
  int kx = tid>>6, nn = tid&63;     // Xs staging

  for (int k0=0;k0<CHN*3;k0+=16) {
    #pragma unroll
    for (int p=0;p<16;++p)
      Ws[kw][cw + p*16] = w1[(size_t)(cw + p*16)*(CHN*3) + k0 + kw];
    #pragma unroll
    for (int p=0;p<4;++p) {
      int k = k0 + kx + p*4;
      int ci = k/3, r = k - ci*3;
      int tt = t0 + nn + r - 1;
      Xs[kx+p*4][nn] = (tt>=0 && tt<TLEN)
          ? def[((size_t)b*CHN + ci)*TLEN + tt] : 0.f;
    }
    __syncthreads();
    #pragma unroll
    for (int kk=0;kk<16;++kk) {
      float av[16], bv[4];
      #pragma unroll
      for (int i=0;i<16;++i) av[i] = Ws[kk][tr*16 + i];
      #pragma unroll
      for (int j=0;j<4;++j)  bv[j] = Xs[kk][tc*4 + j];
      #pragma unroll
      for (int i=0;i<16;++i)
        #pragma unroll
        for (int j=0;j<4;++j)
          acc[i][j] = fmaf(av[i], bv[j], acc[i][j]);
    }
    __syncthreads();
  }

  // epilogue: part[n] = sum_co relu(H+b1[co]) * w2[co]
  float part[4] = {0.f,0.f,0.f,0.f};
  #pragma unroll
  for (int i=0;i<16;++i) {
    int co = tr*16 + i;
    float bias = b1[co];
    float wv   = w2[co];
    #pragma unroll
    for (int j=0;j<4;++j) {
      float h = acc[i][j] + bias;
      h = h > 0.f ? h : 0.f;
      part[j] = fmaf(h, wv, part[j]);
    }
  }
  if (tid < 64) Ss[tid] = 0.f;
  __syncthreads();
  #pragma unroll
  for (int j=0;j<4;++j) atomicAdd(&Ss[tc*4+j], part[j]);
  __syncthreads();
  if (tid < 64)
    outs[n0 + tid] = Ss[tid] + b2p[0];
}

extern "C" void kernel_launch(void* const* d_in, const int* in_sizes, int n_in,
                              void* d_out, int out_size, void* d_ws, size_t ws_size,
                              hipStream_t stream) {
  const float* x  = (const float*)d_in[0];
  const float* ow = (const float*)d_in[1];
  const float* ob = (const float*)d_in[2];
  const float* mw = (const float*)d_in[3];
  const float* mb = (const float*)d_in[4];
  const float* wg = (const float*)d_in[5];
  const float* w1 = (const float*)d_in[6];
  const float* b1 = (const float*)d_in[7];
  const float* w2 = (const float*)d_in[8];
  const float* b2 = (const float*)d_in[9];

  float* out_def = (float*)d_out;
  float* out_str = out_def + (size_t)BATCH*CHN*TLEN;

  k1<<<dim3(TLEN/64, BATCH), dim3(64,4), 0, stream>>>(x, ow, ob, mw, mb, wg, out_def);
  k2<<<dim3(BATCH*TLEN/64), 256, 0, stream>>>(out_def, w1, b1, w2, b2, out_str);
}

// Round 4
// 650.734 us; speedup vs baseline: 1.3010x; 1.3010x over previous
//
#include <hip/hip_runtime.h>
#include <hip/hip_bf16.h>

#define CHN 512
#define TLEN 2048
#define KSZ 5
#define BATCH 16

typedef short bf16x8 __attribute__((ext_vector_type(8)));   // 8 bf16 (4 VGPRs)
typedef float f32x4  __attribute__((ext_vector_type(4)));

// ---------------------------------------------------------------------------
// k1: fused offset conv (out-ch 0..4), modulator conv (+sigmoid), deformable
// sampling with diagonal weight. FP32 I/O. No scratch.
// grid (TLEN/64, B), block (64 t, 16 c-groups) = 1024 thr -> high occupancy.
// Phase A: conv(k=3,pad=1), 16-way split over ci (32 ci each), LDS tree
//          reduce, build samp[64][5] in LDS.
// Phase B: each thread samples 32 channels at fixed t.
// ---------------------------------------------------------------------------
__global__ __launch_bounds__(1024) void k1(const float* __restrict__ x,
    const float* __restrict__ ow, const float* __restrict__ ob,
    const float* __restrict__ mw, const float* __restrict__ mb,
    const float* __restrict__ wgt, float* __restrict__ out)
{
  int b  = blockIdx.y;
  int t0 = blockIdx.x*64;
  int tx = threadIdx.x;            // t within tile
  int cg = threadIdx.y;            // 0..15
  int t  = t0 + tx;

  __shared__ float  red[16][64][10];
  __shared__ float4 samp[64][KSZ];

  // ---- Phase A ----
  float acc[10];
  #pragma unroll
  for (int i=0;i<10;++i) acc[i]=0.f;
  const float* xb = x + (size_t)b*CHN*TLEN;
  int c0 = cg*32;
  #pragma unroll 4
  for (int c=c0;c<c0+32;++c) {
    const float* xr = xb + (size_t)c*TLEN;
    float xm = (t>0)      ? xr[t-1] : 0.f;
    float xc = xr[t];
    float xp = (t<TLEN-1) ? xr[t+1] : 0.f;
    int wb = c*3;
    #pragma unroll
    for (int o=0;o<5;++o) {
      const float* wo = ow + o*(CHN*3) + wb;
      acc[o]   = fmaf(xm, wo[0], acc[o]);
      acc[o]   = fmaf(xc, wo[1], acc[o]);
      acc[o]   = fmaf(xp, wo[2], acc[o]);
      const float* wm = mw + o*(CHN*3) + wb;
      acc[5+o] = fmaf(xm, wm[0], acc[5+o]);
      acc[5+o] = fmaf(xc, wm[1], acc[5+o]);
      acc[5+o] = fmaf(xp, wm[2], acc[5+o]);
    }
  }
  #pragma unroll
  for (int i=0;i<10;++i) red[cg][tx][i] = acc[i];
  __syncthreads();
  // tree reduce over the 16 c-groups
  for (int s=8;s>0;s>>=1) {
    if (cg < s) {
      #pragma unroll
      for (int i=0;i<10;++i) red[cg][tx][i] += red[cg+s][tx][i];
    }
    __syncthreads();
  }
  if (cg==0) {
    #pragma unroll
    for (int k=0;k<KSZ;++k) {
      float off = red[0][tx][k]   + ob[k];
      float mv  = red[0][tx][5+k] + mb[k];
      float sig = 1.f/(1.f + expf(-mv));
      float pos = (float)(t + k - 2) + off;
      pos = fminf(fmaxf(pos, 0.f), (float)(TLEN-1));
      float pf = floorf(pos), pc = ceilf(pos);
      samp[tx][k] = make_float4(pf, pc, (pc-pos)*sig, (pos-pf)*sig);
    }
  }
  __syncthreads();

  // ---- Phase B ----
  int   idxf[KSZ], idxc[KSZ];
  float wgf[KSZ], wgc[KSZ];
  #pragma unroll
  for (int k=0;k<KSZ;++k) {
    float4 s = samp[tx][k];
    idxf[k] = (int)s.x; idxc[k] = (int)s.y;
    wgf[k]  = s.z;      wgc[k]  = s.w;
  }
  #pragma unroll 2
  for (int c=c0;c<c0+32;++c) {
    const float* xr = xb + (size_t)c*TLEN;
    const float* wd = wgt + (size_t)c*(CHN*KSZ) + (size_t)c*KSZ;  // diag row
    float a = 0.f;
    #pragma unroll
    for (int k=0;k<KSZ;++k) {
      float xf = xr[idxf[k]];
      float xc = xr[idxc[k]];
      a = fmaf(fmaf(xc, wgc[k], xf*wgf[k]), wd[k], a);
    }
    out[((size_t)b*CHN + c)*TLEN + t] = a;
  }
}

// ---------------------------------------------------------------------------
// k2: fused rp1 conv(k=3,pad=1, 512->256) + ReLU + rp2 (256->1) + bias,
// bf16 MFMA 16x16x32. H[co,n] = W1[co,k]*X[k,n], M=256, K=1536, N=32768,
// X[k=ci*3+r, n=(b,t)] = def[b,ci,t+r-1] zero-padded.
// Block: 512 thr (8 waves), BM=256 (full M), BN=128, BK=32. Wave (wM,wN)
// computes 64x64 via 4x4 MFMA tiles. Strength reduced fully in-block.
// fp32->bf16 conversion happens during LDS staging.
// ---------------------------------------------------------------------------
__global__ __launch_bounds__(512) void k2(const float* __restrict__ def,
    const float* __restrict__ w1, const float* __restrict__ b1,
    const float* __restrict__ w2, const float* __restrict__ b2p,
    float* __restrict__ outs)
{
  int n0 = blockIdx.x*128;
  int b  = n0 / TLEN;
  int t0 = n0 % TLEN;              // 128 | 2048: tiles never straddle b
  int tid  = threadIdx.x;
  int lane = tid & 63;
  int wave = tid >> 6;             // 0..7
  int wM   = wave & 3;             // 64-row group
  int wN   = wave >> 2;            // 64-col group
  int ln15 = lane & 15, quad = lane >> 4;

  __shared__ __align__(16) __hip_bfloat16 Ws[256][32];  // [co][k]  16 KB
  __shared__ __align__(16) __hip_bfloat16 Xs[128][32];  // [n][k]    8 KB
  __shared__ float Ss[128];

  f32x4 acc[4][4];
  #pragma unroll
  for (int i=0;i<4;++i)
    #pragma unroll
    for (int j=0;j<4;++j) acc[i][j] = (f32x4){0.f,0.f,0.f,0.f};

  int kg = tid & 7;                // 4-wide k chunk: kk = kg*4..kg*4+3
  int cb = tid >> 3;               // 0..63

  for (int k0=0;k0<CHN*3;k0+=32) {
    // stage W1 (256x32): thread -> rows cb+p*64, cols kg*4..+3
    #pragma unroll
    for (int p=0;p<4;++p) {
      int co = cb + p*64;
      float4 wv = *(const float4*)&w1[(size_t)co*(CHN*3) + k0 + kg*4];
      __hip_bfloat16* wp = &Ws[co][kg*4];
      wp[0] = __float2bfloat16(wv.x);
      wp[1] = __float2bfloat16(wv.y);
      wp[2] = __float2bfloat16(wv.z);
      wp[3] = __float2bfloat16(wv.w);
    }
    // stage X (128x32): thread -> n = cb+p*64, kk = kg*4+j
    #pragma unroll
    for (int p=0;p<2;++p) {
      int n = cb + p*64;
      __hip_bfloat16* xp = &Xs[n][kg*4];
      #pragma unroll
      for (int j=0;j<4;++j) {
        int k  = k0 + kg*4 + j;
        int ci = k/3, r = k - ci*3;
        int tt = t0 + n + r - 1;
        float v = (tt>=0 && tt<TLEN) ? def[((size_t)b*CHN + ci)*TLEN + tt] : 0.f;
        xp[j] = __float2bfloat16(v);
      }
    }
    __syncthreads();
    bf16x8 af[4], bfr[4];
    #pragma unroll
    for (int mt=0;mt<4;++mt)
      af[mt] = *(const bf16x8*)&Ws[wM*64 + mt*16 + ln15][quad*8];
    #pragma unroll
    for (int nt=0;nt<4;++nt)
      bfr[nt] = *(const bf16x8*)&Xs[wN*64 + nt*16 + ln15][quad*8];
    #pragma unroll
    for (int mt=0;mt<4;++mt)
      #pragma unroll
      for (int nt=0;nt<4;++nt)
        acc[mt][nt] = __builtin_amdgcn_mfma_f32_16x16x32_bf16(
            af[mt], bfr[nt], acc[mt][nt], 0, 0, 0);
    __syncthreads();
  }

  // epilogue: strength[n] = sum_co relu(H[co,n]+b1[co]) * w2[co] + b2
  // D layout: col = lane&15, row = quad*4 + reg
  float part[4] = {0.f,0.f,0.f,0.f};
  #pragma unroll
  for (int mt=0;mt<4;++mt) {
    #pragma unroll
    for (int r=0;r<4;++r) {
      int row = wM*64 + mt*16 + quad*4 + r;
      float bias = b1[row];
      float wv   = w2[row];
      #pragma unroll
      for (int nt=0;nt<4;++nt) {
        float h = acc[mt][nt][r] + bias;
        h = fmaxf(h, 0.f);
        part[nt] = fmaf(h, wv, part[nt]);
      }
    }
  }
  if (tid < 128) Ss[tid] = 0.f;
  __syncthreads();
  #pragma unroll
  for (int nt=0;nt<4;++nt)
    atomicAdd(&Ss[wN*64 + nt*16 + ln15], part[nt]);
  __syncthreads();
  if (tid < 128)
    outs[n0 + tid] = Ss[tid] + b2p[0];
}

extern "C" void kernel_launch(void* const* d_in, const int* in_sizes, int n_in,
                              void* d_out, int out_size, void* d_ws, size_t ws_size,
                              hipStream_t stream) {
  const float* x  = (const float*)d_in[0];
  const float* ow = (const float*)d_in[1];
  const float* ob = (const float*)d_in[2];
  const float* mw = (const float*)d_in[3];
  const float* mb = (const float*)d_in[4];
  const float* wg = (const float*)d_in[5];
  const float* w1 = (const float*)d_in[6];
  const float* b1 = (const float*)d_in[7];
  const float* w2 = (const float*)d_in[8];
  const float* b2 = (const float*)d_in[9];

  float* out_def = (float*)d_out;
  float* out_str = out_def + (size_t)BATCH*CHN*TLEN;

  k1<<<dim3(TLEN/64, BATCH), dim3(64,16), 0, stream>>>(x, ow, ob, mw, mb, wg, out_def);
  k2<<<dim3(BATCH*TLEN/128), 512, 0, stream>>>(out_def, w1, b1, w2, b2, out_str);
}

// Round 5
// 370.227 us; speedup vs baseline: 2.2867x; 1.7577x over previous
//
#include <hip/hip_runtime.h>
#include <hip/hip_bf16.h>

#define CHN 512
#define TLEN 2048
#define KSZ 5
#define BATCH 16

typedef __hip_bfloat16 bf16;
typedef short bf16x8 __attribute__((ext_vector_type(8)));   // 8 bf16 (4 VGPRs)
typedef float f32x4  __attribute__((ext_vector_type(4)));

struct __attribute__((packed, aligned(4))) f2u { float x, y; };

// ws layout:
//   samp : float4[B*T*5]                   = 2,621,440 B
//   w1t  : bf16 [16][3][256][40]           =   983,040 B   (pre-tiled W1)
#define SAMP_BYTES (2621440)
#define W1T_ELEMS  (16*3*256*40)

// ---------------------------------------------------------------------------
// kP: w1 fp32 [co][ci][r] -> w1t bf16 [ch][r][co][40] (32 data + 8 pad).
// Flat idx = ((ch*3 + r)*256 + co)*40 + c40. Coalesced writes.
// ---------------------------------------------------------------------------
__global__ __launch_bounds__(256) void kP(const float* __restrict__ w1,
                                          bf16* __restrict__ w1t)
{
  int idx  = blockIdx.x*256 + threadIdx.x;       // < 491520, exact grid
  int c40  = idx % 40;
  int rest = idx / 40;
  int co   = rest & 255;
  int rr   = rest >> 8;          // ch*3 + r
  int r    = rr % 3;
  int ch   = rr / 3;
  float v = 0.f;
  if (c40 < 32) v = w1[(size_t)co*(CHN*3) + (ch*32 + c40)*3 + r];
  w1t[idx] = __float2bfloat16(v);
}

// ---------------------------------------------------------------------------
// kS: offset conv (out 0..4) + modulator conv (+sigmoid) -> sampling params.
// grid (TLEN/64, B), block (64 t, 8 cg). Each thread reduces 64 channels.
// samp[b,t,k] = (gather_base, wf*sig, wc*sig, 0), base = min(floor(pos),2046).
// ---------------------------------------------------------------------------
__global__ __launch_bounds__(512) void kS(const float* __restrict__ x,
    const float* __restrict__ ow, const float* __restrict__ ob,
    const float* __restrict__ mw, const float* __restrict__ mb,
    float4* __restrict__ samp)
{
  int b  = blockIdx.y;
  int t0 = blockIdx.x*64;
  int tx = threadIdx.x;
  int cg = threadIdx.y;            // 0..7
  int t  = t0 + tx;

  __shared__ float red[8][64][10];

  float acc[10];
  #pragma unroll
  for (int i=0;i<10;++i) acc[i]=0.f;
  const float* xb = x + (size_t)b*CHN*TLEN;
  int c0 = cg*64;
  #pragma unroll 2
  for (int c=c0;c<c0+64;++c) {
    const float* xr = xb + (size_t)c*TLEN;
    float xm = (t>0)      ? xr[t-1] : 0.f;
    float xc = xr[t];
    float xp = (t<TLEN-1) ? xr[t+1] : 0.f;
    int wb = c*3;
    #pragma unroll
    for (int o=0;o<5;++o) {
      const float* wo = ow + o*(CHN*3) + wb;
      acc[o]   = fmaf(xm, wo[0], acc[o]);
      acc[o]   = fmaf(xc, wo[1], acc[o]);
      acc[o]   = fmaf(xp, wo[2], acc[o]);
      const float* wm = mw + o*(CHN*3) + wb;
      acc[5+o] = fmaf(xm, wm[0], acc[5+o]);
      acc[5+o] = fmaf(xc, wm[1], acc[5+o]);
      acc[5+o] = fmaf(xp, wm[2], acc[5+o]);
    }
  }
  #pragma unroll
  for (int i=0;i<10;++i) red[cg][tx][i] = acc[i];
  __syncthreads();
  for (int s=4;s>0;s>>=1) {
    if (cg < s) {
      #pragma unroll
      for (int i=0;i<10;++i) red[cg][tx][i] += red[cg+s][tx][i];
    }
    __syncthreads();
  }
  if (cg==0) {
    #pragma unroll
    for (int k=0;k<KSZ;++k) {
      float off = red[0][tx][k]   + ob[k];
      float mv  = red[0][tx][5+k] + mb[k];
      float sig = 1.f/(1.f + expf(-mv));
      float pos = (float)(t + k - 2) + off;
      pos = fminf(fmaxf(pos, 0.f), (float)(TLEN-1));
      float pf = floorf(pos), pc = ceilf(pos);
      int base = min((int)pf, TLEN-2);
      // ref quirk preserved: pos integral -> wf=wc=0 -> contribution 0
      samp[((size_t)b*TLEN + t)*KSZ + k] =
          make_float4((float)base, (pc-pos)*sig, (pos-pf)*sig, 0.f);
    }
  }
}

// ---------------------------------------------------------------------------
// kDf: deformable sampling w/ diagonal weight; pure streaming.
// grid (T/256, C/64, B), block (64 t-lanes, 4 c-bands). Thread owns 4
// consecutive t (float4 store) x 16 c-rows. Gathers are float2 (pf, pf+1).
// Diag weights wave-uniform -> s_load.
// ---------------------------------------------------------------------------
__global__ __launch_bounds__(256) void kDf(const float* __restrict__ x,
    const float* __restrict__ wgt, const float4* __restrict__ sampg,
    float* __restrict__ out)
{
  int b  = blockIdx.z;
  int c0 = blockIdx.y*64;
  int t0 = blockIdx.x*256;
  int tx = threadIdx.x, cy = threadIdx.y;
  int tid = cy*64 + tx;

  __shared__ float4 ss[256*KSZ];     // 20 KB
  for (int i=tid;i<256*KSZ;i+=256)
    ss[i] = sampg[((size_t)b*TLEN + t0)*KSZ + i];
  __syncthreads();

  int   base[4][KSZ];
  float wf[4][KSZ], wc[4][KSZ];
  #pragma unroll
  for (int j=0;j<4;++j)
    #pragma unroll
    for (int k=0;k<KSZ;++k) {
      float4 s = ss[(tx*4+j)*KSZ + k];
      base[j][k] = (int)s.x; wf[j][k] = s.y; wc[j][k] = s.z;
    }

  const float* xb = x + (size_t)b*CHN*TLEN;
  for (int i=0;i<16;++i) {
    int c = c0 + cy*16 + i;
    const float* xr = xb + (size_t)c*TLEN;
    const float* wd = wgt + (size_t)c*(CHN*KSZ) + (size_t)c*KSZ;  // diag row
    float w0 = wd[0], w1v = wd[1], w2v = wd[2], w3 = wd[3], w4 = wd[4];
    float o[4];
    #pragma unroll
    for (int j=0;j<4;++j) {
      float a = 0.f;
      f2u v0 = *(const f2u*)(xr + base[j][0]);
      a = fmaf(fmaf(v0.y, wc[j][0], v0.x*wf[j][0]), w0, a);
      f2u v1 = *(const f2u*)(xr + base[j][1]);
      a = fmaf(fmaf(v1.y, wc[j][1], v1.x*wf[j][1]), w1v, a);
      f2u v2 = *(const f2u*)(xr + base[j][2]);
      a = fmaf(fmaf(v2.y, wc[j][2], v2.x*wf[j][2]), w2v, a);
      f2u v3 = *(const f2u*)(xr + base[j][3]);
      a = fmaf(fmaf(v3.y, wc[j][3], v3.x*wf[j][3]), w3, a);
      f2u v4 = *(const f2u*)(xr + base[j][4]);
      a = fmaf(fmaf(v4.y, wc[j][4], v4.x*wf[j][4]), w4, a);
      o[j] = a;
    }
    float4* op = (float4*)(out + ((size_t)b*CHN + c)*TLEN + t0 + tx*4);
    *op = make_float4(o[0], o[1], o[2], o[3]);
  }
}

// ---------------------------------------------------------------------------
// k2: fused rp1(conv3, 512->256)+ReLU+rp2(256->1)+bias, bf16 MFMA.
// H[co][n] = sum_ci sum_r W1[co][ci][r] * def[ci][t0+n+r-1]  (3 shifted GEMMs
// vs one def tile). Block: 512 thr, BM=256, BN=128, 16 iters of 32-ci chunks.
// Ws staged via global_load_lds DMA from pre-tiled w1t; Dt staged via VGPR
// (fp32->bf16). Rows padded to 40 bf16 (16B-aligned, ~2-way banks).
// ---------------------------------------------------------------------------
__global__ __launch_bounds__(512, 2) void k2(const float* __restrict__ def,
    const bf16* __restrict__ w1t, const float* __restrict__ b1,
    const float* __restrict__ w2, const float* __restrict__ b2p,
    float* __restrict__ outs)
{
  int n0 = blockIdx.x*128;
  int b  = n0 / TLEN;
  int t0 = n0 % TLEN;
  int tid  = threadIdx.x;
  int lane = tid & 63;
  int wave = tid >> 6;
  int wM   = wave & 3;             // 64-row co group
  int wN   = wave >> 2;            // 64-col n group
  int ln15 = lane & 15, quad = lane >> 4;

  __shared__ bf16 Ws[3*256*40];    // 61440 B
  __shared__ bf16 Dt[130*40];      // 10400 B
  __shared__ float Ss[128];

  f32x4 acc[4][4];
  #pragma unroll
  for (int i=0;i<4;++i)
    #pragma unroll
    for (int j=0;j<4;++j) acc[i][j] = (f32x4){0.f,0.f,0.f,0.f};

  for (int ch=0; ch<16; ++ch) {
    // --- async DMA: Ws <- w1t chunk (61440 B, 16B/lane, wave-uniform bases)
    const char* gsrc = (const char*)(w1t + (size_t)ch*(3*256*40));
    for (int of = tid*16; of < 61440; of += 8192) {
      __builtin_amdgcn_global_load_lds(
          (const __attribute__((address_space(1))) unsigned int*)(gsrc + of),
          (__attribute__((address_space(3))) unsigned int*)((char*)Ws + of),
          16, 0, 0);
    }
    // --- VGPR staging: Dt[tt][ci] <- def[ci0+ci][t0-1+tt], 32x130
    int ci0 = ch*32;
    #pragma unroll
    for (int j=0;j<9;++j) {
      int idx = tid + j*512;
      if (idx < 4160) {
        int ci = idx / 130, tt = idx - ci*130;
        int t = t0 - 1 + tt;
        float v = (t>=0 && t<TLEN)
            ? def[((size_t)b*CHN + ci0 + ci)*TLEN + t] : 0.f;
        Dt[tt*40 + ci] = __float2bfloat16(v);
      }
    }
    __syncthreads();   // drains DMA (vmcnt) + lds writes (lgkm)

    #pragma unroll
    for (int r=0;r<3;++r) {
      bf16x8 af[4], bfr[4];
      #pragma unroll
      for (int mt=0;mt<4;++mt)
        af[mt] = *(const bf16x8*)&Ws[(size_t)(r*256 + wM*64 + mt*16 + ln15)*40 + quad*8];
      #pragma unroll
      for (int nt=0;nt<4;++nt)
        bfr[nt] = *(const bf16x8*)&Dt[(size_t)(wN*64 + nt*16 + ln15 + r)*40 + quad*8];
      #pragma unroll
      for (int mt=0;mt<4;++mt)
        #pragma unroll
        for (int nt=0;nt<4;++nt)
          acc[mt][nt] = __builtin_amdgcn_mfma_f32_16x16x32_bf16(
              af[mt], bfr[nt], acc[mt][nt], 0, 0, 0);
    }
    __syncthreads();   // protect Ws/Dt before next chunk overwrites
  }

  // epilogue: strength[n] = sum_co relu(H[co][n]+b1[co]) * w2[co] + b2
  // D layout: col = lane&15 (n), row = quad*4 + reg (co)
  float part[4] = {0.f,0.f,0.f,0.f};
  #pragma unroll
  for (int mt=0;mt<4;++mt) {
    #pragma unroll
    for (int rr=0;rr<4;++rr) {
      int row = wM*64 + mt*16 + quad*4 + rr;
      float bias = b1[row];
      float wv   = w2[row];
      #pragma unroll
      for (int nt=0;nt<4;++nt) {
        float h = acc[mt][nt][rr] + bias;
        h = fmaxf(h, 0.f);
        part[nt] = fmaf(h, wv, part[nt]);
      }
    }
  }
  if (tid < 128) Ss[tid] = 0.f;
  __syncthreads();
  #pragma unroll
  for (int nt=0;nt<4;++nt)
    atomicAdd(&Ss[wN*64 + nt*16 + ln15], part[nt]);
  __syncthreads();
  if (tid < 128)
    outs[n0 + tid] = Ss[tid] + b2p[0];
}

extern "C" void kernel_launch(void* const* d_in, const int* in_sizes, int n_in,
                              void* d_out, int out_size, void* d_ws, size_t ws_size,
                              hipStream_t stream) {
  const float* x  = (const float*)d_in[0];
  const float* ow = (const float*)d_in[1];
  const float* ob = (const float*)d_in[2];
  const float* mw = (const float*)d_in[3];
  const float* mb = (const float*)d_in[4];
  const float* wg = (const float*)d_in[5];
  const float* w1 = (const float*)d_in[6];
  const float* b1 = (const float*)d_in[7];
  const float* w2 = (const float*)d_in[8];
  const float* b2 = (const float*)d_in[9];

  float* out_def = (float*)d_out;
  float* out_str = out_def + (size_t)BATCH*CHN*TLEN;

  float4* samp = (float4*)d_ws;                              // 2.62 MB
  bf16*   w1t  = (bf16*)((char*)d_ws + SAMP_BYTES);          // 983 KB

  kP <<<dim3(W1T_ELEMS/256), 256, 0, stream>>>(w1, w1t);
  kS <<<dim3(TLEN/64, BATCH), dim3(64,8), 0, stream>>>(x, ow, ob, mw, mb, samp);
  kDf<<<dim3(TLEN/256, CHN/64, BATCH), dim3(64,4), 0, stream>>>(x, wg, samp, out_def);
  k2 <<<dim3(BATCH*TLEN/128), 512, 0, stream>>>(out_def, w1t, b1, w2, b2, out_str);
}

// Round 6
// 297.386 us; speedup vs baseline: 2.8468x; 1.2449x over previous
//
#include <hip/hip_runtime.h>
#include <hip/hip_bf16.h>

#define CHN 512
#define TLEN 2048
#define KSZ 5
#define BATCH 16

typedef __hip_bfloat16 bf16;
typedef short bf16x8 __attribute__((ext_vector_type(8)));   // 8 bf16 (4 VGPRs)
typedef float f32x4  __attribute__((ext_vector_type(4)));

struct __attribute__((packed, aligned(4))) f2u { float x, y; };

// ws layout:
//   samp : float4[B*T*5]                   = 2,621,440 B
//   w1t  : bf16 [16][3][256][40]           =   983,040 B   (pre-tiled W1)
//   wpk  : float[512][32]                  =    65,536 B   (packed ow+mw)
#define SAMP_BYTES (2621440)
#define W1T_BYTES  (983040)
#define W1T_ELEMS  (16*3*256*40)

// ---------------------------------------------------------------------------
// kP: w1 fp32 [co][ci][r] -> w1t bf16 [ch][r][co][40] (32 data + 8 pad).
// ---------------------------------------------------------------------------
__global__ __launch_bounds__(256) void kP(const float* __restrict__ w1,
                                          bf16* __restrict__ w1t)
{
  int idx  = blockIdx.x*256 + threadIdx.x;       // < 491520, exact grid
  int c40  = idx % 40;
  int rest = idx / 40;
  int co   = rest & 255;
  int rr   = rest >> 8;          // ch*3 + r
  int r    = rr % 3;
  int ch   = rr / 3;
  float v = 0.f;
  if (c40 < 32) v = w1[(size_t)co*(CHN*3) + (ch*32 + c40)*3 + r];
  w1t[idx] = __float2bfloat16(v);
}

// ---------------------------------------------------------------------------
// kW: pack ow (5x512x3) and mw (5x512x3) -> wpk[c][32]:
//     j in [0,15)  : ow[o][c][d], j = o*3+d
//     j in [15,30) : mw[o][c][d], j = 15 + o*3+d
// 128B-aligned rows so kS can s_load_dwordx8 them.
// ---------------------------------------------------------------------------
__global__ __launch_bounds__(256) void kW(const float* __restrict__ ow,
    const float* __restrict__ mw, float* __restrict__ wpk)
{
  int idx = blockIdx.x*256 + threadIdx.x;        // < 16384, exact grid
  int j = idx & 31, c = idx >> 5;
  float v = 0.f;
  if (j < 15)      { int o = j/3,  d = j - o*3;  v = ow[o*(CHN*3) + c*3 + d]; }
  else if (j < 30) { int jj = j-15; int o = jj/3, d = jj - o*3;
                     v = mw[o*(CHN*3) + c*3 + d]; }
  wpk[idx] = v;
}

// ---------------------------------------------------------------------------
// kS: offset conv (out 0..4) + modulator conv (+sigmoid) -> sampling params.
// grid (TLEN/64, B), block (64 t, 8 cg). Each thread reduces 64 channels.
// Weight reads via readfirstlane-forced SMEM (s_load_dwordx8) -> VMEM pipe
// only carries the 3 x-loads per channel.
// samp[b,t,k] = (gather_base, wf*sig, wc*sig, 0), base = min(floor(pos),2046).
// ---------------------------------------------------------------------------
__global__ __launch_bounds__(512) void kS(const float* __restrict__ x,
    const float* __restrict__ wpk, const float* __restrict__ ob,
    const float* __restrict__ mb, float4* __restrict__ samp)
{
  int b  = blockIdx.y;
  int t0 = blockIdx.x*64;
  int tx = threadIdx.x;
  int cg = threadIdx.y;            // 0..7 (wave-uniform: wave = one tx row)
  int t  = t0 + tx;

  __shared__ float red[8][64][10];

  float acc[10];
  #pragma unroll
  for (int i=0;i<10;++i) acc[i]=0.f;
  const float* xb = x + (size_t)b*CHN*TLEN;
  int c0 = cg*64;
  #pragma unroll 4
  for (int c=c0;c<c0+64;++c) {
    int cu = __builtin_amdgcn_readfirstlane(c);
    const float* wp = wpk + cu*32;             // scalar -> s_load_dwordx8
    const float* xr = xb + (size_t)cu*TLEN;
    float xm = (t>0)      ? xr[t-1] : 0.f;
    float xc = xr[t];
    float xp = (t<TLEN-1) ? xr[t+1] : 0.f;
    #pragma unroll
    for (int o=0;o<5;++o) {
      acc[o]   = fmaf(xm, wp[o*3+0],    acc[o]);
      acc[o]   = fmaf(xc, wp[o*3+1],    acc[o]);
      acc[o]   = fmaf(xp, wp[o*3+2],    acc[o]);
      acc[5+o] = fmaf(xm, wp[15+o*3+0], acc[5+o]);
      acc[5+o] = fmaf(xc, wp[15+o*3+1], acc[5+o]);
      acc[5+o] = fmaf(xp, wp[15+o*3+2], acc[5+o]);
    }
  }
  #pragma unroll
  for (int i=0;i<10;++i) red[cg][tx][i] = acc[i];
  __syncthreads();
  for (int s=4;s>0;s>>=1) {
    if (cg < s) {
      #pragma unroll
      for (int i=0;i<10;++i) red[cg][tx][i] += red[cg+s][tx][i];
    }
    __syncthreads();
  }
  if (cg==0) {
    #pragma unroll
    for (int k=0;k<KSZ;++k) {
      float off = red[0][tx][k]   + ob[k];
      float mv  = red[0][tx][5+k] + mb[k];
      float sig = 1.f/(1.f + expf(-mv));
      float pos = (float)(t + k - 2) + off;
      pos = fminf(fmaxf(pos, 0.f), (float)(TLEN-1));
      float pf = floorf(pos), pc = ceilf(pos);
      int base = min((int)pf, TLEN-2);
      // ref quirk preserved: pos integral -> wf=wc=0 -> contribution 0
      samp[((size_t)b*TLEN + t)*KSZ + k] =
          make_float4((float)base, (pc-pos)*sig, (pos-pf)*sig, 0.f);
    }
  }
}

// ---------------------------------------------------------------------------
// kDf: deformable sampling w/ diagonal weight; pure streaming.
// grid (T/256, C/64, B), block (64 t-lanes, 4 c-bands). Thread owns 4
// consecutive t (float4 store) x 16 c-rows. Gathers are float2 (pf, pf+1).
// ---------------------------------------------------------------------------
__global__ __launch_bounds__(256) void kDf(const float* __restrict__ x,
    const float* __restrict__ wgt, const float4* __restrict__ sampg,
    float* __restrict__ out)
{
  int b  = blockIdx.z;
  int c0 = blockIdx.y*64;
  int t0 = blockIdx.x*256;
  int tx = threadIdx.x, cy = threadIdx.y;
  int tid = cy*64 + tx;

  __shared__ float4 ss[256*KSZ];     // 20 KB
  for (int i=tid;i<256*KSZ;i+=256)
    ss[i] = sampg[((size_t)b*TLEN + t0)*KSZ + i];
  __syncthreads();

  int   base[4][KSZ];
  float wf[4][KSZ], wc[4][KSZ];
  #pragma unroll
  for (int j=0;j<4;++j)
    #pragma unroll
    for (int k=0;k<KSZ;++k) {
      float4 s = ss[(tx*4+j)*KSZ + k];
      base[j][k] = (int)s.x; wf[j][k] = s.y; wc[j][k] = s.z;
    }

  const float* xb = x + (size_t)b*CHN*TLEN;
  for (int i=0;i<16;++i) {
    int c = c0 + cy*16 + i;
    const float* xr = xb + (size_t)c*TLEN;
    const float* wd = wgt + (size_t)c*(CHN*KSZ) + (size_t)c*KSZ;  // diag row
    float w0 = wd[0], w1v = wd[1], w2v = wd[2], w3 = wd[3], w4 = wd[4];
    float o[4];
    #pragma unroll
    for (int j=0;j<4;++j) {
      float a = 0.f;
      f2u v0 = *(const f2u*)(xr + base[j][0]);
      a = fmaf(fmaf(v0.y, wc[j][0], v0.x*wf[j][0]), w0, a);
      f2u v1 = *(const f2u*)(xr + base[j][1]);
      a = fmaf(fmaf(v1.y, wc[j][1], v1.x*wf[j][1]), w1v, a);
      f2u v2 = *(const f2u*)(xr + base[j][2]);
      a = fmaf(fmaf(v2.y, wc[j][2], v2.x*wf[j][2]), w2v, a);
      f2u v3 = *(const f2u*)(xr + base[j][3]);
      a = fmaf(fmaf(v3.y, wc[j][3], v3.x*wf[j][3]), w3, a);
      f2u v4 = *(const f2u*)(xr + base[j][4]);
      a = fmaf(fmaf(v4.y, wc[j][4], v4.x*wf[j][4]), w4, a);
      o[j] = a;
    }
    float4* op = (float4*)(out + ((size_t)b*CHN + c)*TLEN + t0 + tx*4);
    *op = make_float4(o[0], o[1], o[2], o[3]);
  }
}

// ---------------------------------------------------------------------------
// k2: fused rp1(conv3, 512->256)+ReLU+rp2(256->1)+bias, bf16 MFMA.
// H[co][n] = sum_ci sum_r W1[co][ci][r] * def[ci][t0+n+r-1]  (3 shifted GEMMs
// vs one def tile). Block: 512 thr, BM=256, BN=128, 16 iters of 32-ci chunks.
// ---------------------------------------------------------------------------
__global__ __launch_bounds__(512, 2) void k2(const float* __restrict__ def,
    const bf16* __restrict__ w1t, const float* __restrict__ b1,
    const float* __restrict__ w2, const float* __restrict__ b2p,
    float* __restrict__ outs)
{
  int n0 = blockIdx.x*128;
  int b  = n0 / TLEN;
  int t0 = n0 % TLEN;
  int tid  = threadIdx.x;
  int lane = tid & 63;
  int wave = tid >> 6;
  int wM   = wave & 3;             // 64-row co group
  int wN   = wave >> 2;            // 64-col n group
  int ln15 = lane & 15, quad = lane >> 4;

  __shared__ bf16 Ws[3*256*40];    // 61440 B
  __shared__ bf16 Dt[130*40];      // 10400 B
  __shared__ float Ss[128];

  f32x4 acc[4][4];
  #pragma unroll
  for (int i=0;i<4;++i)
    #pragma unroll
    for (int j=0;j<4;++j) acc[i][j] = (f32x4){0.f,0.f,0.f,0.f};

  for (int ch=0; ch<16; ++ch) {
    // --- async DMA: Ws <- w1t chunk (61440 B, 16B/lane, wave-uniform bases)
    const char* gsrc = (const char*)(w1t + (size_t)ch*(3*256*40));
    for (int of = tid*16; of < 61440; of += 8192) {
      __builtin_amdgcn_global_load_lds(
          (const __attribute__((address_space(1))) unsigned int*)(gsrc + of),
          (__attribute__((address_space(3))) unsigned int*)((char*)Ws + of),
          16, 0, 0);
    }
    // --- VGPR staging: Dt[tt][ci] <- def[ci0+ci][t0-1+tt], 32x130
    int ci0 = ch*32;
    #pragma unroll
    for (int j=0;j<9;++j) {
      int idx = tid + j*512;
      if (idx < 4160) {
        int ci = idx / 130, tt = idx - ci*130;
        int t = t0 - 1 + tt;
        float v = (t>=0 && t<TLEN)
            ? def[((size_t)b*CHN + ci0 + ci)*TLEN + t] : 0.f;
        Dt[tt*40 + ci] = __float2bfloat16(v);
      }
    }
    __syncthreads();   // drains DMA (vmcnt) + lds writes (lgkm)

    #pragma unroll
    for (int r=0;r<3;++r) {
      bf16x8 af[4], bfr[4];
      #pragma unroll
      for (int mt=0;mt<4;++mt)
        af[mt] = *(const bf16x8*)&Ws[(size_t)(r*256 + wM*64 + mt*16 + ln15)*40 + quad*8];
      #pragma unroll
      for (int nt=0;nt<4;++nt)
        bfr[nt] = *(const bf16x8*)&Dt[(size_t)(wN*64 + nt*16 + ln15 + r)*40 + quad*8];
      #pragma unroll
      for (int mt=0;mt<4;++mt)
        #pragma unroll
        for (int nt=0;nt<4;++nt)
          acc[mt][nt] = __builtin_amdgcn_mfma_f32_16x16x32_bf16(
              af[mt], bfr[nt], acc[mt][nt], 0, 0, 0);
    }
    __syncthreads();   // protect Ws/Dt before next chunk overwrites
  }

  // epilogue: strength[n] = sum_co relu(H[co][n]+b1[co]) * w2[co] + b2
  float part[4] = {0.f,0.f,0.f,0.f};
  #pragma unroll
  for (int mt=0;mt<4;++mt) {
    #pragma unroll
    for (int rr=0;rr<4;++rr) {
      int row = wM*64 + mt*16 + quad*4 + rr;
      float bias = b1[row];
      float wv   = w2[row];
      #pragma unroll
      for (int nt=0;nt<4;++nt) {
        float h = acc[mt][nt][rr] + bias;
        h = fmaxf(h, 0.f);
        part[nt] = fmaf(h, wv, part[nt]);
      }
    }
  }
  if (tid < 128) Ss[tid] = 0.f;
  __syncthreads();
  #pragma unroll
  for (int nt=0;nt<4;++nt)
    atomicAdd(&Ss[wN*64 + nt*16 + ln15], part[nt]);
  __syncthreads();
  if (tid < 128)
    outs[n0 + tid] = Ss[tid] + b2p[0];
}

extern "C" void kernel_launch(void* const* d_in, const int* in_sizes, int n_in,
                              void* d_out, int out_size, void* d_ws, size_t ws_size,
                              hipStream_t stream) {
  const float* x  = (const float*)d_in[0];
  const float* ow = (const float*)d_in[1];
  const float* ob = (const float*)d_in[2];
  const float* mw = (const float*)d_in[3];
  const float* mb = (const float*)d_in[4];
  const float* wg = (const float*)d_in[5];
  const float* w1 = (const float*)d_in[6];
  const float* b1 = (const float*)d_in[7];
  const float* w2 = (const float*)d_in[8];
  const float* b2 = (const float*)d_in[9];

  float* out_def = (float*)d_out;
  float* out_str = out_def + (size_t)BATCH*CHN*TLEN;

  float4* samp = (float4*)d_ws;                              // 2.62 MB
  bf16*   w1t  = (bf16*)((char*)d_ws + SAMP_BYTES);          // 983 KB
  float*  wpk  = (float*)((char*)d_ws + SAMP_BYTES + W1T_BYTES); // 64 KB

  kP <<<dim3(W1T_ELEMS/256), 256, 0, stream>>>(w1, w1t);
  kW <<<dim3(64), 256, 0, stream>>>(ow, mw, wpk);
  kS <<<dim3(TLEN/64, BATCH), dim3(64,8), 0, stream>>>(x, wpk, ob, mb, samp);
  kDf<<<dim3(TLEN/256, CHN/64, BATCH), dim3(64,4), 0, stream>>>(x, wg, samp, out_def);
  k2 <<<dim3(BATCH*TLEN/128), 512, 0, stream>>>(out_def, w1t, b1, w2, b2, out_str);
}